// Round 8
// baseline (2000.721 us; speedup 1.0000x reference)
//
#include <hip/hip_runtime.h>
#include <cstdint>
#include <math.h>

// ---------------- problem constants ----------------
static constexpr int NB  = 8;
static constexpr int CC_ = 256;          // channels
static constexpr int HH  = 100, WW = 100, HW = 10000;
static constexpr int KA  = 9;
static constexpr int AN  = HW * KA;      // 90000 anchors/image
static constexpr int PRE  = 3000;
static constexpr int POST = 300;
static constexpr int NW64 = 47;          // ceil(3000/64)
static constexpr float NMS_T = 0.7f;
static constexpr int SCH = 22;           // selection chunks per image (22*4096 >= 90000)

typedef float v2f __attribute__((ext_vector_type(2)));

__device__ __forceinline__ v2f fma2(v2f a, v2f b, v2f c) {
#if __has_builtin(__builtin_elementwise_fma)
  return __builtin_elementwise_fma(a, b, c);
#else
  v2f r; r[0] = fmaf(a[0], b[0], c[0]); r[1] = fmaf(a[1], b[1], c[1]); return r;
#endif
}

// d_out layout (float offsets)
static constexpr size_t OUT_CLS  = 0;            // 8*2*90000 = 1,440,000
static constexpr size_t OUT_REG  = 1440000;      // 8*90000*4 = 2,880,000
static constexpr size_t OUT_ROIS = 4320000;      // 2400*4
static constexpr size_t OUT_RIND = 4329600;      // 2400
static constexpr size_t OUT_ANCH = 4332000;      // 90000*4

// workspace layout (byte offsets, all 16B-aligned)
static constexpr size_t WS_H     = 0;                          // 81,920,000
static constexpr size_t WS_WT    = 81920000;                   //  2,359,296
static constexpr size_t WS_W54   = WS_WT   + 2359296;          //     55,296
static constexpr size_t WS_BOXES = WS_W54  + 55296;            // 11,520,000
static constexpr size_t WS_KEYS  = WS_BOXES+ 11520000;         //  2,880,000
static constexpr size_t WS_SBOX  = WS_KEYS + 2880000;          //    384,000
static constexpr size_t WS_SVAL  = WS_SBOX + 384000;           //     96,000
static constexpr size_t WS_MASK  = WS_SVAL + 96000;            //  9,048,064
static constexpr size_t WS_KEEPW = WS_MASK + (size_t)8*3008*47*8; //   4,096
static constexpr size_t WS_HIST1 = WS_KEEPW + 4096;            //     32,768
static constexpr size_t WS_HIST2 = WS_HIST1 + 32768;           //     32,768
static constexpr size_t WS_SEL   = WS_HIST2 + 32768;           //        128  (8 x {B1,A1,B2,cnt})
static constexpr size_t WS_CAND  = WS_SEL + 128;               //    262,144

// anchor heights/widths per k = r_idx*3 + s_idx  (fp32 of f64-exact values)
__device__ __constant__ float AHC[9] = {
  90.50966799187809f, 181.01933598375618f, 362.03867196751236f,
  128.f, 256.f, 512.f,
  181.01933598375618f, 362.03867196751236f, 724.0773439350247f };
__device__ __constant__ float AWC[9] = {
  181.01933598375618f, 362.03867196751236f, 724.0773439350247f,
  128.f, 256.f, 512.f,
  90.50966799187809f, 181.01933598375618f, 362.03867196751236f };

// ---------------- prep: weights to [cotile][ci][kk][co128] (block-linear) ----------------
__global__ void k_prep_w1(const float* __restrict__ w1, float* __restrict__ wT2) {
  int t = blockIdx.x * 256 + threadIdx.x;
  if (t >= 2 * 256 * 9 * 128) return;
  int cotile = t / 294912;
  int rem = t % 294912;
  int ci = rem / 1152;
  int r2 = rem % 1152;
  int kk = r2 / 128;
  int col = r2 % 128;
  int co = cotile * 128 + col;
  wT2[t] = w1[(size_t)co * 2304 + ci * 9 + kk];
}

// ---------------- prep: head weights [ci][54] + anchors output ----------------
__global__ void k_prep_small(const float* __restrict__ wc, const float* __restrict__ wr,
                             float* __restrict__ w54, float* __restrict__ anch) {
  int t = blockIdx.x * 256 + threadIdx.x;
  if (t < 256 * 54) {
    int ci = t / 54, j = t % 54;
    w54[t] = (j < 18) ? wc[j * 256 + ci] : wr[(j - 18) * 256 + ci];
  }
  int u = t - 256 * 54;
  if (u >= 0 && u < AN) {
    int k = u % KA; int pp = u / KA; int y = pp / WW; int x = pp % WW;
    int ri = k / 3, si = k % 3;
    double scale = (double)(8 << si);
    double r = (ri == 0) ? 0.5 : ((ri == 1) ? 1.0 : 2.0);
    double hh = 16.0 * scale * sqrt(r);
    double ww = 16.0 * scale * sqrt(1.0 / r);
    double sy = y * 16.0, sx = x * 16.0;
    anch[(size_t)u * 4 + 0] = (float)(sy + 8.0 - hh * 0.5);
    anch[(size_t)u * 4 + 1] = (float)(sx + 8.0 - ww * 0.5);
    anch[(size_t)u * 4 + 2] = (float)(sy + 8.0 + hh * 0.5);
    anch[(size_t)u * 4 + 3] = (float)(sx + 8.0 + ww * 0.5);
  }
}

// ---------------- conv 3x3 pad 1 + bias + relu ----------------
// UNCHANGED from R7 (1295 us, VGPR 80, 0 bank conflicts, no spill).
// __launch_bounds__(256,3): DO NOT RAISE — (256,6) spilled accumulators (R6: 14x slower).
// FMA chain per accumulator is (ci asc, ky, kx), pk-paired co — bit-exact vs R1.
__global__ __launch_bounds__(256, 3) void k_conv3x3(const float* __restrict__ x,
    const float* __restrict__ wT2, const float* __restrict__ b1,
    float* __restrict__ hout) {
  __shared__ float sx[4][10][18];
  __shared__ float sw[4 * 9 * 128];
  const int tid = threadIdx.x;
  const int xt = blockIdx.x % 7, yt = blockIdx.x / 7;
  const int cotile = blockIdx.y;
  const int n = blockIdx.z;
  const int x0 = xt * 16, y0 = yt * 8;
  const int tx = tid & 15, g = tid >> 4;

  int slot[3];
  #pragma unroll
  for (int k = 0; k < 3; ++k) {
    int e = tid + 256 * k;
    int c = e / 180; int rem = e - c * 180;
    int row = rem / 18; int col = rem - row * 18;
    int gy = y0 - 1 + row, gx = x0 - 1 + col;
    bool st = (e < 720);
    bool ok = st && gy >= 0 && gy < HH && gx >= 0 && gx < WW;
    int goff = ok ? (c * HW + gy * WW + gx) : 0;
    int lds = st ? (c * 180 + row * 18 + col) : 0;
    slot[k] = goff | (lds << 17) | (ok ? (1 << 28) : 0) | (st ? (1 << 29) : 0);
  }

  v2f acc2[4][8];
  #pragma unroll
  for (int a = 0; a < 4; ++a)
    #pragma unroll
    for (int b = 0; b < 8; ++b) { acc2[a][b][0] = 0.f; acc2[a][b][1] = 0.f; }

  const float* xn = x + (size_t)n * CC_ * HW;
  const float4* wbase4 = (const float4*)(wT2 + (size_t)cotile * (256 * 9 * 128));

  for (int ch = 0; ch < 64; ++ch) {
    const int ci0 = ch * 4;
    __syncthreads();
    #pragma unroll
    for (int k = 0; k < 3; ++k) {
      if (slot[k] & (1 << 29)) {
        float v = 0.f;
        if (slot[k] & (1 << 28)) v = xn[ci0 * HW + (slot[k] & 0x1FFFF)];
        ((float*)sx)[(slot[k] >> 17) & 0x7FF] = v;
      }
    }
    const float4* wp = wbase4 + (size_t)ci0 * 288;
    #pragma unroll
    for (int k = 0; k < 5; ++k) {
      int e = tid + 256 * k;
      if (e < 1152) ((float4*)sw)[e] = wp[e];
    }
    __syncthreads();

    for (int c = 0; c < 4; ++c) {
      const float* sxc = &sx[c][0][tx];
      const float* swc = sw + c * 1152 + g * 8;
      float xr[10][3];
      #pragma unroll
      for (int r = 0; r < 10; ++r) {
        #pragma unroll
        for (int kx = 0; kx < 3; ++kx) xr[r][kx] = sxc[r * 18 + kx];
      }
      #pragma unroll
      for (int ky = 0; ky < 3; ++ky) {
        #pragma unroll
        for (int kx = 0; kx < 3; ++kx) {
          const v2f* swv = (const v2f*)(swc + (ky * 3 + kx) * 128);
          const v2f w0 = swv[0], w1 = swv[1], w2 = swv[2], w3 = swv[3];
          #pragma unroll
          for (int yy = 0; yy < 8; ++yy) {
            float xv = xr[yy + ky][kx];
            v2f xv2; xv2[0] = xv; xv2[1] = xv;
            acc2[0][yy] = fma2(w0, xv2, acc2[0][yy]);
            acc2[1][yy] = fma2(w1, xv2, acc2[1][yy]);
            acc2[2][yy] = fma2(w2, xv2, acc2[2][yy]);
            acc2[3][yy] = fma2(w3, xv2, acc2[3][yy]);
          }
        }
      }
    }
  }
  const int gx = x0 + tx;
  if (gx < WW) {
    #pragma unroll
    for (int p = 0; p < 4; ++p) {
      #pragma unroll
      for (int cm = 0; cm < 2; ++cm) {
        int co = cotile * 128 + g * 8 + 2 * p + cm;
        float bias = b1[co];
        #pragma unroll
        for (int yy = 0; yy < 8; ++yy) {
          int gy = y0 + yy;
          if (gy < HH) {
            float v = acc2[p][yy][cm] + bias;
            hout[((size_t)(n * CC_ + co) * HH + gy) * WW + gx] = fmaxf(v, 0.f);
          }
        }
      }
    }
  }
}

// ---------------- 1x1 heads + decode + score keys ----------------
// REVERTED to R1/R3 version: w54 addresses are thread-uniform -> compiler emits
// s_load (SMEM) — measured faster than the R4 LDS-staged variant (tail 534 vs 686).
__global__ __launch_bounds__(256) void k_heads(const float* __restrict__ hin,
    const float* __restrict__ w54, const float* __restrict__ bc, const float* __restrict__ br,
    const int* __restrict__ imw, const int* __restrict__ imh,
    float* __restrict__ cls_out, float* __restrict__ reg_out,
    float* __restrict__ boxes, unsigned int* __restrict__ keys) {
  int gid = blockIdx.x * 256 + threadIdx.x;
  if (gid >= NB * HW) return;
  int n = gid / HW, p = gid % HW;
  float cacc[18], racc[36];
  #pragma unroll
  for (int j = 0; j < 18; ++j) cacc[j] = 0.f;
  #pragma unroll
  for (int j = 0; j < 36; ++j) racc[j] = 0.f;
  const float* hp = hin + (size_t)n * CC_ * HW + p;
  #pragma unroll 2
  for (int ci = 0; ci < CC_; ++ci) {
    float hv = hp[(size_t)ci * HW];
    const float* wrow = w54 + ci * 54;
    #pragma unroll
    for (int j = 0; j < 18; ++j) cacc[j] = fmaf(hv, wrow[j], cacc[j]);
    #pragma unroll
    for (int j = 0; j < 36; ++j) racc[j] = fmaf(hv, wrow[18 + j], racc[j]);
  }
  const float imgW = (float)imw[0], imgH = (float)imh[0];
  const int y = p / WW, xq = p % WW;
  #pragma unroll
  for (int k = 0; k < 9; ++k) {
    float c0 = cacc[2 * k] + bc[2 * k];
    float c1 = cacc[2 * k + 1] + bc[2 * k + 1];
    int a = p * 9 + k;
    cls_out[(size_t)n * 2 * AN + a]      = c0;
    cls_out[(size_t)n * 2 * AN + AN + a] = c1;
    float t0 = racc[4 * k]     + br[4 * k];
    float t1 = racc[4 * k + 1] + br[4 * k + 1];
    float t2 = racc[4 * k + 2] + br[4 * k + 2];
    float t3 = racc[4 * k + 3] + br[4 * k + 3];
    size_t ro = ((size_t)n * AN + a) * 4;
    reg_out[ro] = t0; reg_out[ro + 1] = t1; reg_out[ro + 2] = t2; reg_out[ro + 3] = t3;
    float hk = AHC[k], wk = AWC[k];
    float cy = fmaf(t0, hk, y  * 16.f + 8.f);
    float cx = fmaf(t1, wk, xq * 16.f + 8.f);
    float bh = expf(t2) * hk, bw = expf(t3) * wk;
    float y1 = cy - 0.5f * bh, x1 = cx - 0.5f * bw;
    float y2 = cy + 0.5f * bh, x2 = cx + 0.5f * bw;
    y1 = fminf(fmaxf(y1, 0.f), imgH); y2 = fminf(fmaxf(y2, 0.f), imgH);
    x1 = fminf(fmaxf(x1, 0.f), imgW); x2 = fminf(fmaxf(x2, 0.f), imgW);
    bool valid = (y2 - y1 >= 16.f) && (x2 - x1 >= 16.f);
    boxes[ro] = y1; boxes[ro + 1] = x1; boxes[ro + 2] = y2; boxes[ro + 3] = x2;
    float dc = c1 - c0;                       // monotone in softmax fg
    unsigned u = __float_as_uint(dc);
    u = (u & 0x80000000u) ? ~u : (u | 0x80000000u);
    keys[(size_t)n * AN + a] = valid ? u : 0u;
  }
}

// ---------------- parallel top-3000 selection pipeline ----------------
// Semantics identical to the old single-block k_select: two-level 10+10-bit
// histogram threshold, then stable sort by (mapped_score desc, idx asc).
__global__ void k_zero(unsigned* __restrict__ h1, unsigned* __restrict__ h2,
                       int* __restrict__ sel) {
  int t = blockIdx.x * 256 + threadIdx.x;
  if (t < 8192) { h1[t] = 0; h2[t] = 0; }
  if (t < 32) sel[t] = 0;
}

__global__ __launch_bounds__(256) void k_hist1(const unsigned* __restrict__ keys,
    unsigned* __restrict__ hist1) {
  __shared__ unsigned lh[4][1024];
  const int t = threadIdx.x, n = blockIdx.y;
  const int start = blockIdx.x * 4096;
  const int end = min(start + 4096, AN);
  for (int i = t; i < 4096; i += 256) ((unsigned*)lh)[i] = 0;
  __syncthreads();
  const unsigned* kp = keys + (size_t)n * AN;
  const int rep = t & 3;
  for (int i = start + t; i < end; i += 256) atomicAdd(&lh[rep][kp[i] >> 22], 1u);
  __syncthreads();
  for (int b = t; b < 1024; b += 256) {
    unsigned s = lh[0][b] + lh[1][b] + lh[2][b] + lh[3][b];
    if (s) atomicAdd(&hist1[n * 1024 + b], s);
  }
}

__global__ __launch_bounds__(1024) void k_scan1(const unsigned* __restrict__ hist1,
    int* __restrict__ sel) {
  __shared__ unsigned sc[1024];
  const int t = threadIdx.x, n = blockIdx.x;
  unsigned myc = hist1[n * 1024 + t];
  sc[t] = myc;
  __syncthreads();
  for (int off = 1; off < 1024; off <<= 1) {
    unsigned add = (t + off < 1024) ? sc[t + off] : 0;
    __syncthreads();
    sc[t] += add;
    __syncthreads();
  }
  unsigned incl = sc[t];
  unsigned above = incl - myc;
  if (above < (unsigned)PRE && incl >= (unsigned)PRE && myc > 0) {
    sel[n * 4 + 0] = t;
    sel[n * 4 + 1] = (int)above;
  }
}

__global__ __launch_bounds__(256) void k_hist2(const unsigned* __restrict__ keys,
    const int* __restrict__ sel, unsigned* __restrict__ hist2) {
  __shared__ unsigned lh[4][1024];
  const int t = threadIdx.x, n = blockIdx.y;
  const int B1 = sel[n * 4 + 0];
  const int start = blockIdx.x * 4096;
  const int end = min(start + 4096, AN);
  for (int i = t; i < 4096; i += 256) ((unsigned*)lh)[i] = 0;
  __syncthreads();
  const unsigned* kp = keys + (size_t)n * AN;
  const int rep = t & 3;
  for (int i = start + t; i < end; i += 256) {
    unsigned k32 = kp[i];
    if ((int)(k32 >> 22) == B1) atomicAdd(&lh[rep][(k32 >> 12) & 1023u], 1u);
  }
  __syncthreads();
  for (int b = t; b < 1024; b += 256) {
    unsigned s = lh[0][b] + lh[1][b] + lh[2][b] + lh[3][b];
    if (s) atomicAdd(&hist2[n * 1024 + b], s);
  }
}

__global__ __launch_bounds__(1024) void k_scan2(const unsigned* __restrict__ hist2,
    int* __restrict__ sel) {
  __shared__ unsigned sc[1024];
  const int t = threadIdx.x, n = blockIdx.x;
  unsigned myc = hist2[n * 1024 + t];
  sc[t] = myc;
  __syncthreads();
  for (int off = 1; off < 1024; off <<= 1) {
    unsigned add = (t + off < 1024) ? sc[t + off] : 0;
    __syncthreads();
    sc[t] += add;
    __syncthreads();
  }
  unsigned incl = sc[t];
  unsigned above = incl - myc;
  const int target = PRE - sel[n * 4 + 1];
  if ((int)above < target && (int)incl >= target && myc > 0)
    sel[n * 4 + 2] = t;
}

__global__ __launch_bounds__(256) void k_compact(const unsigned* __restrict__ keys,
    int* __restrict__ sel, unsigned long long* __restrict__ cand) {
  const int t = threadIdx.x, n = blockIdx.y;
  const int B1 = sel[n * 4 + 0], B2 = sel[n * 4 + 2];
  const int start = blockIdx.x * 4096;
  const int end = min(start + 4096, AN);
  const unsigned* kp = keys + (size_t)n * AN;
  for (int i = start + t; i < end; i += 256) {
    unsigned k32 = kp[i];
    int b1 = (int)(k32 >> 22);
    bool s = (b1 > B1) || (b1 == B1 && (int)((k32 >> 12) & 1023u) >= B2);
    if (s) {
      int pos = atomicAdd(&sel[n * 4 + 3], 1);
      if (pos < 4096)
        cand[(size_t)n * 4096 + pos] =
            ((unsigned long long)k32 << 32) | (unsigned long long)(0xFFFFFFFFu - (unsigned)i);
    }
  }
}

__global__ __launch_bounds__(1024) void k_sortsel(const unsigned long long* __restrict__ cand,
    const int* __restrict__ sel, const float* __restrict__ boxes,
    float* __restrict__ sbox, int* __restrict__ sval) {
  __shared__ unsigned long long c[4096];
  const int t = threadIdx.x, n = blockIdx.x;
  int cnt = sel[n * 4 + 3]; if (cnt > 4096) cnt = 4096;
  for (int i = t; i < 4096; i += 1024)
    c[i] = (i < cnt) ? cand[(size_t)n * 4096 + i] : 0ull;
  __syncthreads();
  for (int k = 2; k <= 4096; k <<= 1) {
    for (int j = k >> 1; j > 0; j >>= 1) {
      for (int i = t; i < 4096; i += 1024) {
        int ixj = i ^ j;
        if (ixj > i) {
          unsigned long long va = c[i], vb = c[ixj];
          bool desc = ((i & k) == 0);
          if (desc ? (va < vb) : (va > vb)) { c[i] = vb; c[ixj] = va; }
        }
      }
      __syncthreads();
    }
  }
  for (int i = t; i < PRE; i += 1024) {
    unsigned long long kv = c[i];
    unsigned idx = 0xFFFFFFFFu - (unsigned)(kv & 0xFFFFFFFFull);
    float4 bb = *(const float4*)(boxes + ((size_t)n * AN + idx) * 4);
    *(float4*)(sbox + ((size_t)n * PRE + i) * 4) = bb;
    sval[n * PRE + i] = ((kv >> 32) != 0ull) ? 1 : 0;
  }
}

// ---------------- NMS suppression bitmask (64x64 tiles) ----------------
__global__ __launch_bounds__(64) void k_mask(const float* __restrict__ sbox,
    unsigned long long* __restrict__ mask) {
  __shared__ float4 jb[64];
  const int t = threadIdx.x;
  const int jt = blockIdx.x, it = blockIdx.y, n = blockIdx.z;
  const int j0 = jt * 64;
  int jg = j0 + t;
  float4 v = make_float4(0.f, 0.f, 0.f, 0.f);
  if (jg < PRE) v = *(const float4*)(sbox + ((size_t)n * PRE + jg) * 4);
  jb[t] = v;
  __syncthreads();
  const int i = it * 64 + t;
  if (i >= PRE) return;
  float4 bi = *(const float4*)(sbox + ((size_t)n * PRE + i) * 4);
  float areaI = (bi.z - bi.x) * (bi.w - bi.y);
  unsigned long long bits = 0ull;
  #pragma unroll 4
  for (int jj = 0; jj < 64; ++jj) {
    int j = j0 + jj;
    float4 bj = jb[jj];
    float yy1 = fmaxf(bi.x, bj.x), xx1 = fmaxf(bi.y, bj.y);
    float yy2 = fminf(bi.z, bj.z), xx2 = fminf(bi.w, bj.w);
    float inter = fmaxf(yy2 - yy1, 0.f) * fmaxf(xx2 - xx1, 0.f);
    float areaJ = (bj.z - bj.x) * (bj.w - bj.y);
    float iou = inter / (areaI + areaJ - inter + 1e-9f);
    if (iou > NMS_T && j > i && j < PRE) bits |= (1ull << jj);
  }
  mask[((size_t)n * 3008 + i) * NW64 + jt] = bits;
}

// ---------------- sequential greedy NMS scan (1 wave / image) ----------------
__global__ __launch_bounds__(64) void k_nms_seq(const unsigned long long* __restrict__ mask,
    const int* __restrict__ sval, unsigned long long* __restrict__ keepW) {
  const int t = threadIdx.x, n = blockIdx.x;
  __shared__ unsigned long long kws[NW64];
  for (int w = 0; w < NW64; ++w) {
    int i = w * 64 + t;
    int v = (i < PRE) ? sval[n * PRE + i] : 0;
    unsigned long long m = __ballot(v != 0);
    if (t == 0) kws[w] = m;
  }
  __syncthreads();
  unsigned long long keep = (t < NW64) ? kws[t] : 0ull;
  const unsigned long long* mrow = mask + (size_t)n * 3008 * NW64;
  unsigned long long buf[16];
  #pragma unroll
  for (int r = 0; r < 16; ++r)
    buf[r] = (t < NW64) ? mrow[(size_t)r * NW64 + t] : 0ull;
  for (int base = 0; base < PRE; base += 16) {
    #pragma unroll
    for (int r = 0; r < 16; ++r) {
      int i = base + r;
      if (i < PRE) {
        unsigned long long kb = __shfl(keep, i >> 6);
        if ((kb >> (i & 63)) & 1ull) keep &= ~buf[r];
      }
      int nx = i + 16;
      buf[r] = (nx < PRE && t < NW64) ? mrow[(size_t)nx * NW64 + t] : 0ull;
    }
  }
  if (t < NW64) keepW[n * 64 + t] = keep;
}

// ---------------- finalize: rank-compact top-300, zero-fill, roi_inds ----------------
__global__ __launch_bounds__(256) void k_final(const unsigned long long* __restrict__ keepW,
    const float* __restrict__ sbox, float* __restrict__ rois, float* __restrict__ rind) {
  __shared__ unsigned long long kw[NW64];
  __shared__ int pref[NW64 + 1];
  const int t = threadIdx.x, n = blockIdx.x;
  if (t < NW64) kw[t] = keepW[n * 64 + t];
  __syncthreads();
  if (t == 0) {
    int s = 0;
    for (int w = 0; w < NW64; ++w) { pref[w] = s; s += __popcll(kw[w]); }
    pref[NW64] = s;
  }
  for (int e = t; e < POST * 4; e += 256) rois[(size_t)n * POST * 4 + e] = 0.f;
  for (int e = t; e < POST; e += 256) rind[(size_t)n * POST + e] = (float)n;
  __syncthreads();
  for (int i = t; i < PRE; i += 256) {
    int wd = i >> 6, b = i & 63;
    unsigned long long wv = kw[wd];
    if ((wv >> b) & 1ull) {
      int rank = pref[wd] + __popcll(wv & ((1ull << b) - 1ull));
      if (rank < POST) {
        float4 bb = *(const float4*)(sbox + ((size_t)n * PRE + i) * 4);
        *(float4*)(rois + ((size_t)n * POST + rank) * 4) = bb;
      }
    }
  }
}

// ---------------- launch ----------------
extern "C" void kernel_launch(void* const* d_in, const int* in_sizes, int n_in,
                              void* d_out, int out_size, void* d_ws, size_t ws_size,
                              hipStream_t stream) {
  const float* x  = (const float*)d_in[0];
  const float* w1 = (const float*)d_in[1];
  const float* b1 = (const float*)d_in[2];
  const float* wc = (const float*)d_in[3];
  const float* bc = (const float*)d_in[4];
  const float* wr = (const float*)d_in[5];
  const float* br = (const float*)d_in[6];
  const int* imw  = (const int*)d_in[7];
  const int* imh  = (const int*)d_in[8];
  float* out = (float*)d_out;
  char* ws = (char*)d_ws;
  float* hbuf = (float*)(ws + WS_H);
  float* wT2  = (float*)(ws + WS_WT);
  float* w54  = (float*)(ws + WS_W54);
  float* boxes = (float*)(ws + WS_BOXES);
  unsigned* keys = (unsigned*)(ws + WS_KEYS);
  float* sbox = (float*)(ws + WS_SBOX);
  int* sval   = (int*)(ws + WS_SVAL);
  unsigned long long* mask  = (unsigned long long*)(ws + WS_MASK);
  unsigned long long* keepW = (unsigned long long*)(ws + WS_KEEPW);
  unsigned* hist1 = (unsigned*)(ws + WS_HIST1);
  unsigned* hist2 = (unsigned*)(ws + WS_HIST2);
  int* sel = (int*)(ws + WS_SEL);
  unsigned long long* cand = (unsigned long long*)(ws + WS_CAND);

  k_prep_w1<<<2304, 256, 0, stream>>>(w1, wT2);
  k_prep_small<<<406, 256, 0, stream>>>(wc, wr, w54, out + OUT_ANCH);
  k_zero<<<33, 256, 0, stream>>>(hist1, hist2, sel);
  k_conv3x3<<<dim3(91, 2, NB), 256, 0, stream>>>(x, wT2, b1, hbuf);
  k_heads<<<313, 256, 0, stream>>>(hbuf, w54, bc, br, imw, imh,
                                   out + OUT_CLS, out + OUT_REG, boxes, keys);
  k_hist1<<<dim3(SCH, NB), 256, 0, stream>>>(keys, hist1);
  k_scan1<<<NB, 1024, 0, stream>>>(hist1, sel);
  k_hist2<<<dim3(SCH, NB), 256, 0, stream>>>(keys, sel, hist2);
  k_scan2<<<NB, 1024, 0, stream>>>(hist2, sel);
  k_compact<<<dim3(SCH, NB), 256, 0, stream>>>(keys, sel, cand);
  k_sortsel<<<NB, 1024, 0, stream>>>(cand, sel, boxes, sbox, sval);
  k_mask<<<dim3(NW64, NW64, NB), 64, 0, stream>>>(sbox, mask);
  k_nms_seq<<<NB, 64, 0, stream>>>(mask, sval, keepW);
  k_final<<<NB, 256, 0, stream>>>(keepW, sbox, out + OUT_ROIS, out + OUT_RIND);
}

// Round 9
// 1887.262 us; speedup vs baseline: 1.0601x; 1.0601x over previous
//
#include <hip/hip_runtime.h>
#include <cstdint>
#include <math.h>

// ---------------- problem constants ----------------
static constexpr int NB  = 8;
static constexpr int CC_ = 256;          // channels
static constexpr int HH  = 100, WW = 100, HW = 10000;
static constexpr int KA  = 9;
static constexpr int AN  = HW * KA;      // 90000 anchors/image
static constexpr int PRE  = 3000;
static constexpr int POST = 300;
static constexpr int NW64 = 47;          // ceil(3000/64)
static constexpr float NMS_T = 0.7f;

typedef float v2f __attribute__((ext_vector_type(2)));

__device__ __forceinline__ v2f fma2(v2f a, v2f b, v2f c) {
#if __has_builtin(__builtin_elementwise_fma)
  return __builtin_elementwise_fma(a, b, c);
#else
  v2f r; r[0] = fmaf(a[0], b[0], c[0]); r[1] = fmaf(a[1], b[1], c[1]); return r;
#endif
}

// d_out layout (float offsets)
static constexpr size_t OUT_CLS  = 0;            // 8*2*90000 = 1,440,000
static constexpr size_t OUT_REG  = 1440000;      // 8*90000*4 = 2,880,000
static constexpr size_t OUT_ROIS = 4320000;      // 2400*4
static constexpr size_t OUT_RIND = 4329600;      // 2400
static constexpr size_t OUT_ANCH = 4332000;      // 90000*4

// workspace layout (byte offsets, all 16B-aligned)
static constexpr size_t WS_H     = 0;                          // 81,920,000
static constexpr size_t WS_WT    = 81920000;                   //  2,359,296
static constexpr size_t WS_W54   = WS_WT   + 2359296;          //     55,296
static constexpr size_t WS_BOXES = WS_W54  + 55296;            // 11,520,000
static constexpr size_t WS_KEYS  = WS_BOXES+ 11520000;         //  2,880,000
static constexpr size_t WS_SBOX  = WS_KEYS + 2880000;          //    384,000
static constexpr size_t WS_SVAL  = WS_SBOX + 384000;           //     96,000
static constexpr size_t WS_MASK  = WS_SVAL + 96000;            //  9,048,064

// anchor heights/widths per k = r_idx*3 + s_idx  (fp32 of f64-exact values)
__device__ __constant__ float AHC[9] = {
  90.50966799187809f, 181.01933598375618f, 362.03867196751236f,
  128.f, 256.f, 512.f,
  181.01933598375618f, 362.03867196751236f, 724.0773439350247f };
__device__ __constant__ float AWC[9] = {
  181.01933598375618f, 362.03867196751236f, 724.0773439350247f,
  128.f, 256.f, 512.f,
  90.50966799187809f, 181.01933598375618f, 362.03867196751236f };

// ---------------- prep (single kernel): w1 transpose + head weights + anchors ----------------
__global__ void k_prep_all(const float* __restrict__ w1, const float* __restrict__ wc,
                           const float* __restrict__ wr, float* __restrict__ wT2,
                           float* __restrict__ w54, float* __restrict__ anch) {
  int t = blockIdx.x * 256 + threadIdx.x;
  if (t < 2 * 256 * 9 * 128) {
    int cotile = t / 294912;
    int rem = t % 294912;
    int ci = rem / 1152;
    int r2 = rem % 1152;
    int kk = r2 / 128;
    int col = r2 % 128;
    int co = cotile * 128 + col;
    wT2[t] = w1[(size_t)co * 2304 + ci * 9 + kk];
  }
  if (t < 256 * 54) {
    int ci = t / 54, j = t % 54;
    w54[t] = (j < 18) ? wc[j * 256 + ci] : wr[(j - 18) * 256 + ci];
  }
  int u = t - 256 * 54;
  if (u >= 0 && u < AN) {
    int k = u % KA; int pp = u / KA; int y = pp / WW; int x = pp % WW;
    int ri = k / 3, si = k % 3;
    double scale = (double)(8 << si);
    double r = (ri == 0) ? 0.5 : ((ri == 1) ? 1.0 : 2.0);
    double hh = 16.0 * scale * sqrt(r);
    double ww = 16.0 * scale * sqrt(1.0 / r);
    double sy = y * 16.0, sx = x * 16.0;
    anch[(size_t)u * 4 + 0] = (float)(sy + 8.0 - hh * 0.5);
    anch[(size_t)u * 4 + 1] = (float)(sx + 8.0 - ww * 0.5);
    anch[(size_t)u * 4 + 2] = (float)(sy + 8.0 + hh * 0.5);
    anch[(size_t)u * 4 + 3] = (float)(sx + 8.0 + ww * 0.5);
  }
}

// ---------------- conv 3x3 pad 1 + bias + relu ----------------
// UNCHANGED from R7/R8 (1300 us, VGPR 80, 0 bank conflicts, no spill).
// __launch_bounds__(256,3): DO NOT RAISE — (256,6) spilled accumulators (R6: 14x slower).
// FMA chain per accumulator is (ci asc, ky, kx), pk-paired co — bit-exact vs R1.
__global__ __launch_bounds__(256, 3) void k_conv3x3(const float* __restrict__ x,
    const float* __restrict__ wT2, const float* __restrict__ b1,
    float* __restrict__ hout) {
  __shared__ float sx[4][10][18];
  __shared__ float sw[4 * 9 * 128];
  const int tid = threadIdx.x;
  const int xt = blockIdx.x % 7, yt = blockIdx.x / 7;
  const int cotile = blockIdx.y;
  const int n = blockIdx.z;
  const int x0 = xt * 16, y0 = yt * 8;
  const int tx = tid & 15, g = tid >> 4;

  int slot[3];
  #pragma unroll
  for (int k = 0; k < 3; ++k) {
    int e = tid + 256 * k;
    int c = e / 180; int rem = e - c * 180;
    int row = rem / 18; int col = rem - row * 18;
    int gy = y0 - 1 + row, gx = x0 - 1 + col;
    bool st = (e < 720);
    bool ok = st && gy >= 0 && gy < HH && gx >= 0 && gx < WW;
    int goff = ok ? (c * HW + gy * WW + gx) : 0;
    int lds = st ? (c * 180 + row * 18 + col) : 0;
    slot[k] = goff | (lds << 17) | (ok ? (1 << 28) : 0) | (st ? (1 << 29) : 0);
  }

  v2f acc2[4][8];
  #pragma unroll
  for (int a = 0; a < 4; ++a)
    #pragma unroll
    for (int b = 0; b < 8; ++b) { acc2[a][b][0] = 0.f; acc2[a][b][1] = 0.f; }

  const float* xn = x + (size_t)n * CC_ * HW;
  const float4* wbase4 = (const float4*)(wT2 + (size_t)cotile * (256 * 9 * 128));

  for (int ch = 0; ch < 64; ++ch) {
    const int ci0 = ch * 4;
    __syncthreads();
    #pragma unroll
    for (int k = 0; k < 3; ++k) {
      if (slot[k] & (1 << 29)) {
        float v = 0.f;
        if (slot[k] & (1 << 28)) v = xn[ci0 * HW + (slot[k] & 0x1FFFF)];
        ((float*)sx)[(slot[k] >> 17) & 0x7FF] = v;
      }
    }
    const float4* wp = wbase4 + (size_t)ci0 * 288;
    #pragma unroll
    for (int k = 0; k < 5; ++k) {
      int e = tid + 256 * k;
      if (e < 1152) ((float4*)sw)[e] = wp[e];
    }
    __syncthreads();

    for (int c = 0; c < 4; ++c) {
      const float* sxc = &sx[c][0][tx];
      const float* swc = sw + c * 1152 + g * 8;
      float xr[10][3];
      #pragma unroll
      for (int r = 0; r < 10; ++r) {
        #pragma unroll
        for (int kx = 0; kx < 3; ++kx) xr[r][kx] = sxc[r * 18 + kx];
      }
      #pragma unroll
      for (int ky = 0; ky < 3; ++ky) {
        #pragma unroll
        for (int kx = 0; kx < 3; ++kx) {
          const v2f* swv = (const v2f*)(swc + (ky * 3 + kx) * 128);
          const v2f w0 = swv[0], w1 = swv[1], w2 = swv[2], w3 = swv[3];
          #pragma unroll
          for (int yy = 0; yy < 8; ++yy) {
            float xv = xr[yy + ky][kx];
            v2f xv2; xv2[0] = xv; xv2[1] = xv;
            acc2[0][yy] = fma2(w0, xv2, acc2[0][yy]);
            acc2[1][yy] = fma2(w1, xv2, acc2[1][yy]);
            acc2[2][yy] = fma2(w2, xv2, acc2[2][yy]);
            acc2[3][yy] = fma2(w3, xv2, acc2[3][yy]);
          }
        }
      }
    }
  }
  const int gx = x0 + tx;
  if (gx < WW) {
    #pragma unroll
    for (int p = 0; p < 4; ++p) {
      #pragma unroll
      for (int cm = 0; cm < 2; ++cm) {
        int co = cotile * 128 + g * 8 + 2 * p + cm;
        float bias = b1[co];
        #pragma unroll
        for (int yy = 0; yy < 8; ++yy) {
          int gy = y0 + yy;
          if (gy < HH) {
            float v = acc2[p][yy][cm] + bias;
            hout[((size_t)(n * CC_ + co) * HH + gy) * WW + gx] = fmaxf(v, 0.f);
          }
        }
      }
    }
  }
}

// ---------------- 1x1 heads + decode + score keys (R1/R3 version, proven) ----------------
__global__ __launch_bounds__(256) void k_heads(const float* __restrict__ hin,
    const float* __restrict__ w54, const float* __restrict__ bc, const float* __restrict__ br,
    const int* __restrict__ imw, const int* __restrict__ imh,
    float* __restrict__ cls_out, float* __restrict__ reg_out,
    float* __restrict__ boxes, unsigned int* __restrict__ keys) {
  int gid = blockIdx.x * 256 + threadIdx.x;
  if (gid >= NB * HW) return;
  int n = gid / HW, p = gid % HW;
  float cacc[18], racc[36];
  #pragma unroll
  for (int j = 0; j < 18; ++j) cacc[j] = 0.f;
  #pragma unroll
  for (int j = 0; j < 36; ++j) racc[j] = 0.f;
  const float* hp = hin + (size_t)n * CC_ * HW + p;
  #pragma unroll 2
  for (int ci = 0; ci < CC_; ++ci) {
    float hv = hp[(size_t)ci * HW];
    const float* wrow = w54 + ci * 54;
    #pragma unroll
    for (int j = 0; j < 18; ++j) cacc[j] = fmaf(hv, wrow[j], cacc[j]);
    #pragma unroll
    for (int j = 0; j < 36; ++j) racc[j] = fmaf(hv, wrow[18 + j], racc[j]);
  }
  const float imgW = (float)imw[0], imgH = (float)imh[0];
  const int y = p / WW, xq = p % WW;
  #pragma unroll
  for (int k = 0; k < 9; ++k) {
    float c0 = cacc[2 * k] + bc[2 * k];
    float c1 = cacc[2 * k + 1] + bc[2 * k + 1];
    int a = p * 9 + k;
    cls_out[(size_t)n * 2 * AN + a]      = c0;
    cls_out[(size_t)n * 2 * AN + AN + a] = c1;
    float t0 = racc[4 * k]     + br[4 * k];
    float t1 = racc[4 * k + 1] + br[4 * k + 1];
    float t2 = racc[4 * k + 2] + br[4 * k + 2];
    float t3 = racc[4 * k + 3] + br[4 * k + 3];
    size_t ro = ((size_t)n * AN + a) * 4;
    reg_out[ro] = t0; reg_out[ro + 1] = t1; reg_out[ro + 2] = t2; reg_out[ro + 3] = t3;
    float hk = AHC[k], wk = AWC[k];
    float cy = fmaf(t0, hk, y  * 16.f + 8.f);
    float cx = fmaf(t1, wk, xq * 16.f + 8.f);
    float bh = expf(t2) * hk, bw = expf(t3) * wk;
    float y1 = cy - 0.5f * bh, x1 = cx - 0.5f * bw;
    float y2 = cy + 0.5f * bh, x2 = cx + 0.5f * bw;
    y1 = fminf(fmaxf(y1, 0.f), imgH); y2 = fminf(fmaxf(y2, 0.f), imgH);
    x1 = fminf(fmaxf(x1, 0.f), imgW); x2 = fminf(fmaxf(x2, 0.f), imgW);
    bool valid = (y2 - y1 >= 16.f) && (x2 - x1 >= 16.f);
    boxes[ro] = y1; boxes[ro + 1] = x1; boxes[ro + 2] = y2; boxes[ro + 3] = x2;
    float dc = c1 - c0;                       // monotone in softmax fg
    unsigned u = __float_as_uint(dc);
    u = (u & 0x80000000u) ? ~u : (u | 0x80000000u);
    keys[(size_t)n * AN + a] = valid ? u : 0u;
  }
}

// ---------------- per-image stable top-3000 selection (monolithic, proven R3/R7) ----------------
__global__ __launch_bounds__(1024) void k_select(const unsigned* __restrict__ keys,
    const float* __restrict__ boxes, float* __restrict__ sbox, int* __restrict__ sval) {
  __shared__ unsigned hist[4][1024];
  __shared__ unsigned long long cand[4096];
  __shared__ int sB1, sA1, sB2, scnt;
  const int t = threadIdx.x;
  const int n = blockIdx.x;
  const unsigned* kp = keys + (size_t)n * AN;
  for (int i = t; i < 4096; i += 1024) ((unsigned*)hist)[i] = 0;
  __syncthreads();
  const int rep = (t >> 6) & 3;
  for (int i = t; i < AN; i += 1024) atomicAdd(&hist[rep][kp[i] >> 22], 1u);
  __syncthreads();
  unsigned myc = hist[0][t] + hist[1][t] + hist[2][t] + hist[3][t];
  __syncthreads();
  hist[0][t] = myc;
  __syncthreads();
  for (int off = 1; off < 1024; off <<= 1) {
    unsigned add = (t + off < 1024) ? hist[0][t + off] : 0;
    __syncthreads();
    hist[0][t] += add;
    __syncthreads();
  }
  unsigned incl = hist[0][t];
  unsigned above = incl - myc;
  if (above < (unsigned)PRE && incl >= (unsigned)PRE && myc > 0) { sB1 = t; sA1 = (int)above; }
  __syncthreads();
  const int B1 = sB1, A1 = sA1;
  __syncthreads();
  hist[0][t] = 0;
  __syncthreads();
  for (int i = t; i < AN; i += 1024) {
    unsigned k32 = kp[i];
    if ((int)(k32 >> 22) == B1) atomicAdd(&hist[0][(k32 >> 12) & 1023u], 1u);
  }
  __syncthreads();
  myc = hist[0][t];
  __syncthreads();
  for (int off = 1; off < 1024; off <<= 1) {
    unsigned add = (t + off < 1024) ? hist[0][t + off] : 0;
    __syncthreads();
    hist[0][t] += add;
    __syncthreads();
  }
  incl = hist[0][t]; above = incl - myc;
  const int target = PRE - A1;
  if ((int)above < target && (int)incl >= target && myc > 0) sB2 = t;
  if (t == 0) scnt = 0;
  __syncthreads();
  const int B2 = sB2;
  for (int i = t; i < AN; i += 1024) {
    unsigned k32 = kp[i];
    int b1 = (int)(k32 >> 22);
    bool sel = (b1 > B1) || (b1 == B1 && (int)((k32 >> 12) & 1023u) >= B2);
    if (sel) {
      int pos = atomicAdd(&scnt, 1);
      if (pos < 4096)
        cand[pos] = ((unsigned long long)k32 << 32) | (unsigned long long)(0xFFFFFFFFu - (unsigned)i);
    }
  }
  __syncthreads();
  int cnt = scnt; if (cnt > 4096) cnt = 4096;
  for (int i = cnt + t; i < 4096; i += 1024) cand[i] = 0ull;
  __syncthreads();
  // bitonic sort descending: key = (score_mapped, ~idx)  => score desc, idx asc
  for (int k = 2; k <= 4096; k <<= 1) {
    for (int j = k >> 1; j > 0; j >>= 1) {
      for (int i = t; i < 4096; i += 1024) {
        int ixj = i ^ j;
        if (ixj > i) {
          unsigned long long va = cand[i], vb = cand[ixj];
          bool desc = ((i & k) == 0);
          if (desc ? (va < vb) : (va > vb)) { cand[i] = vb; cand[ixj] = va; }
        }
      }
      __syncthreads();
    }
  }
  for (int i = t; i < PRE; i += 1024) {
    unsigned long long kv = cand[i];
    unsigned idx = 0xFFFFFFFFu - (unsigned)(kv & 0xFFFFFFFFull);
    float4 bb = *(const float4*)(boxes + ((size_t)n * AN + idx) * 4);
    *(float4*)(sbox + ((size_t)n * PRE + i) * 4) = bb;
    sval[n * PRE + i] = ((kv >> 32) != 0ull) ? 1 : 0;
  }
}

// ---------------- NMS suppression bitmask: 4 i-tiles per 256-thread block ----------------
__global__ __launch_bounds__(256) void k_mask(const float* __restrict__ sbox,
    unsigned long long* __restrict__ mask) {
  __shared__ float4 jb[64];
  const int t = threadIdx.x;
  const int lane = t & 63, wv = t >> 6;
  const int jt = blockIdx.x, n = blockIdx.z;
  const int it = blockIdx.y * 4 + wv;
  const int j0 = jt * 64;
  if (t < 64) {
    int jg = j0 + t;
    float4 v = make_float4(0.f, 0.f, 0.f, 0.f);
    if (jg < PRE) v = *(const float4*)(sbox + ((size_t)n * PRE + jg) * 4);
    jb[t] = v;
  }
  __syncthreads();
  const int i = it * 64 + lane;
  if (it >= NW64 || i >= PRE) return;
  float4 bi = *(const float4*)(sbox + ((size_t)n * PRE + i) * 4);
  float areaI = (bi.z - bi.x) * (bi.w - bi.y);
  unsigned long long bits = 0ull;
  #pragma unroll 4
  for (int jj = 0; jj < 64; ++jj) {
    int j = j0 + jj;
    float4 bj = jb[jj];
    float yy1 = fmaxf(bi.x, bj.x), xx1 = fmaxf(bi.y, bj.y);
    float yy2 = fminf(bi.z, bj.z), xx2 = fminf(bi.w, bj.w);
    float inter = fmaxf(yy2 - yy1, 0.f) * fmaxf(xx2 - xx1, 0.f);
    float areaJ = (bj.z - bj.x) * (bj.w - bj.y);
    float iou = inter / (areaI + areaJ - inter + 1e-9f);
    if (iou > NMS_T && j > i && j < PRE) bits |= (1ull << jj);
  }
  mask[((size_t)n * 3008 + i) * NW64 + jt] = bits;
}

// ---------------- fused: sequential greedy NMS scan + rank-compact top-300 ----------------
__global__ __launch_bounds__(256) void k_nms_final(const unsigned long long* __restrict__ mask,
    const int* __restrict__ sval, const float* __restrict__ sbox,
    float* __restrict__ rois, float* __restrict__ rind) {
  __shared__ unsigned long long kws[NW64];
  __shared__ int pref[NW64 + 1];
  const int t = threadIdx.x, n = blockIdx.x;
  // phase 1: wave 0 does the serial greedy scan (identical semantics to k_nms_seq)
  if (t < 64) {
    unsigned long long keep = 0ull;
    for (int w = 0; w < NW64; ++w) {
      int i = w * 64 + t;
      int v = (i < PRE) ? sval[n * PRE + i] : 0;
      unsigned long long m = __ballot(v != 0);
      if (t == w) keep = m;     // in-register, no LDS round-trip needed (single wave)
    }
    const unsigned long long* mrow = mask + (size_t)n * 3008 * NW64;
    unsigned long long buf[16];
    #pragma unroll
    for (int r = 0; r < 16; ++r)
      buf[r] = (t < NW64) ? mrow[(size_t)r * NW64 + t] : 0ull;
    for (int base = 0; base < PRE; base += 16) {
      #pragma unroll
      for (int r = 0; r < 16; ++r) {
        int i = base + r;
        if (i < PRE) {
          unsigned long long kb = __shfl(keep, i >> 6);
          if ((kb >> (i & 63)) & 1ull) keep &= ~buf[r];
        }
        int nx = i + 16;
        buf[r] = (nx < PRE && t < NW64) ? mrow[(size_t)nx * NW64 + t] : 0ull;
      }
    }
    if (t < NW64) kws[t] = keep;
  }
  __syncthreads();
  // phase 2: all threads — identical to k_final
  if (t == 0) {
    int s = 0;
    for (int w = 0; w < NW64; ++w) { pref[w] = s; s += __popcll(kws[w]); }
    pref[NW64] = s;
  }
  for (int e = t; e < POST * 4; e += 256) rois[(size_t)n * POST * 4 + e] = 0.f;
  for (int e = t; e < POST; e += 256) rind[(size_t)n * POST + e] = (float)n;
  __syncthreads();
  for (int i = t; i < PRE; i += 256) {
    int wd = i >> 6, b = i & 63;
    unsigned long long wv = kws[wd];
    if ((wv >> b) & 1ull) {
      int rank = pref[wd] + __popcll(wv & ((1ull << b) - 1ull));
      if (rank < POST) {
        float4 bb = *(const float4*)(sbox + ((size_t)n * PRE + i) * 4);
        *(float4*)(rois + ((size_t)n * POST + rank) * 4) = bb;
      }
    }
  }
}

// ---------------- launch (6 kernels total) ----------------
extern "C" void kernel_launch(void* const* d_in, const int* in_sizes, int n_in,
                              void* d_out, int out_size, void* d_ws, size_t ws_size,
                              hipStream_t stream) {
  const float* x  = (const float*)d_in[0];
  const float* w1 = (const float*)d_in[1];
  const float* b1 = (const float*)d_in[2];
  const float* wc = (const float*)d_in[3];
  const float* bc = (const float*)d_in[4];
  const float* wr = (const float*)d_in[5];
  const float* br = (const float*)d_in[6];
  const int* imw  = (const int*)d_in[7];
  const int* imh  = (const int*)d_in[8];
  float* out = (float*)d_out;
  char* ws = (char*)d_ws;
  float* hbuf = (float*)(ws + WS_H);
  float* wT2  = (float*)(ws + WS_WT);
  float* w54  = (float*)(ws + WS_W54);
  float* boxes = (float*)(ws + WS_BOXES);
  unsigned* keys = (unsigned*)(ws + WS_KEYS);
  float* sbox = (float*)(ws + WS_SBOX);
  int* sval   = (int*)(ws + WS_SVAL);
  unsigned long long* mask  = (unsigned long long*)(ws + WS_MASK);

  k_prep_all<<<2304, 256, 0, stream>>>(w1, wc, wr, wT2, w54, out + OUT_ANCH);
  k_conv3x3<<<dim3(91, 2, NB), 256, 0, stream>>>(x, wT2, b1, hbuf);
  k_heads<<<313, 256, 0, stream>>>(hbuf, w54, bc, br, imw, imh,
                                   out + OUT_CLS, out + OUT_REG, boxes, keys);
  k_select<<<NB, 1024, 0, stream>>>(keys, boxes, sbox, sval);
  k_mask<<<dim3(NW64, 12, NB), 256, 0, stream>>>(sbox, mask);
  k_nms_final<<<NB, 256, 0, stream>>>(mask, sval, sbox, out + OUT_ROIS, out + OUT_RIND);
}